// Round 2
// baseline (241.691 us; speedup 1.0000x reference)
//
#include <hip/hip_runtime.h>

// Problem constants
#define BB 4
#define CC 64
#define NN 4096
#define DKK 8
#define JSPLIT 4

// ws layout (floats):
//  qws  [B][N][8]          @ 0         131072
//  kws  [B][N][8]          @ 131072    131072
//  vws  [B][N][64]         @ 262144    1048576
//  pout [JSPLIT*B][64][N]  @ 1310720   4194304
//  pl   [JSPLIT*B][N]      @ 5505024   65536
// total 5,570,560 floats = 22.3 MB

// ---------------------------------------------------------------------------
// Kernel 1: fused 1x1 convs. q,k,v -> ws (fp32), x1 -> d_out (fp32).
// grid 256 (b * 64 n-tiles), block 256. Each thread: one n, 36 of 144 outputs.
// ---------------------------------------------------------------------------
__global__ __launch_bounds__(256) void proj_kernel(
    const float* __restrict__ x,
    const float* __restrict__ Wq, const float* __restrict__ bq,
    const float* __restrict__ Wk, const float* __restrict__ bk,
    const float* __restrict__ Wv, const float* __restrict__ bv,
    const float* __restrict__ W1, const float* __restrict__ b1,
    float* __restrict__ qws, float* __restrict__ kws, float* __restrict__ vws,
    float* __restrict__ out)
{
    __shared__ float Wl[144 * 68];   // rows padded 64->68 (bank decorrelation)
    __shared__ float bl[144];
    __shared__ float xl[64 * 64];

    const int tid = threadIdx.x;

    // stage weights: concatenated [Wq(512) | Wk(512) | Wv(4096) | W1(4096)]
    #pragma unroll
    for (int r = 0; r < 36; ++r) {
        int idx = tid + r * 256;           // 0..9215
        int row = idx >> 6, col = idx & 63;
        float w;
        if (idx < 512)        w = Wq[idx];
        else if (idx < 1024)  w = Wk[idx - 512];
        else if (idx < 5120)  w = Wv[idx - 1024];
        else                  w = W1[idx - 5120];
        Wl[row * 68 + col] = w;
    }
    if (tid < 144) {
        float v;
        if (tid < 8)        v = bq[tid];
        else if (tid < 16)  v = bk[tid - 8];
        else if (tid < 80)  v = bv[tid - 16];
        else                v = b1[tid - 80];
        bl[tid] = v;
    }

    const int blk = blockIdx.x;            // 0..255
    const int b  = blk >> 6;
    const int n0 = (blk & 63) * 64;

    // stage x tile [64c][64n]
    #pragma unroll
    for (int r = 0; r < 16; ++r) {
        int idx = tid + r * 256;           // 0..4095
        int c = idx >> 6, nn = idx & 63;
        xl[c * 64 + nn] = x[(b * 64 + c) * NN + n0 + nn];
    }
    __syncthreads();

    const int n_loc = tid >> 2;
    const int t4    = tid & 3;
    const int n     = n0 + n_loc;

    float xr[64];
    #pragma unroll
    for (int c = 0; c < 64; ++c) xr[c] = xl[c * 64 + n_loc];

    for (int oi = 0; oi < 36; ++oi) {
        const int o = t4 * 36 + oi;
        const float4* Wrow = (const float4*)&Wl[o * 68];
        float acc = bl[o];
        #pragma unroll
        for (int c4 = 0; c4 < 16; ++c4) {
            float4 w = Wrow[c4];
            acc += w.x * xr[4 * c4 + 0] + w.y * xr[4 * c4 + 1]
                 + w.z * xr[4 * c4 + 2] + w.w * xr[4 * c4 + 3];
        }
        if (o < 8)        qws[(b * NN + n) * 8 + o] = acc;
        else if (o < 16)  kws[(b * NN + n) * 8 + (o - 8)] = acc;
        else if (o < 80)  vws[(b * NN + n) * 64 + (o - 16)] = acc;
        else              out[(b * 64 + (o - 80)) * NN + n] = acc;
    }
}

// ---------------------------------------------------------------------------
// Kernel 2: attention, flash-style single-pass (no max subtraction; energies
// are ~N(0,1), max over 16M ~ 6, exp() safe in fp32).
// grid 1024 = 4 jsplit x 4 b x 64 i-tiles; block 256 = 64 queries.
// Partial numerator -> pout[s][b][c][n], partial denominator -> pl[s][b][n].
// ---------------------------------------------------------------------------
__global__ __launch_bounds__(256) void attn_kernel(
    const float* __restrict__ qws, const float* __restrict__ kws,
    const float* __restrict__ vws,
    float* __restrict__ pout, float* __restrict__ pl)
{
    __shared__ float kl[64 * 8];      // 2 KB
    __shared__ float vl[64 * 64];     // 16 KB
    __shared__ float plds[64 * 64];   // p[j][i], 16 KB

    const int tid = threadIdx.x;
    const int blk = blockIdx.x;       // 0..1023
    const int it  = blk & 63;
    const int b   = (blk >> 6) & 3;
    const int js  = blk >> 8;
    const int i0  = it * 64;

    // energy-phase role: 64 i x 4 j-subsets
    const int i_e  = tid >> 2;
    const int jsub = tid & 3;
    float qreg[8];
    {
        const float4* qp = (const float4*)&qws[(b * NN + i0 + i_e) * 8];
        float4 q0 = qp[0], q1 = qp[1];
        qreg[0] = q0.x; qreg[1] = q0.y; qreg[2] = q0.z; qreg[3] = q0.w;
        qreg[4] = q1.x; qreg[5] = q1.y; qreg[6] = q1.z; qreg[7] = q1.w;
    }
    float lsum = 0.f;

    // PV-phase role: 4 i's x 4 c's per thread
    const int c0 = (tid >> 4) * 4;
    const int ip = (tid & 15) * 4;
    float acc[16];
    #pragma unroll
    for (int i = 0; i < 16; ++i) acc[i] = 0.f;

    for (int t = 0; t < 16; ++t) {
        const int j0 = js * 1024 + t * 64;

        // stage k tile (512 floats) and v tile (4096 floats)
        {
            const float2* src = (const float2*)&kws[(size_t)(b * NN + j0) * 8];
            ((float2*)kl)[tid] = src[tid];
        }
        {
            const float4* src = (const float4*)&vws[(size_t)(b * NN + j0) * 64];
            float4* dst = (float4*)vl;
            dst[tid]       = src[tid];
            dst[tid + 256] = src[tid + 256];
            dst[tid + 512] = src[tid + 512];
            dst[tid + 768] = src[tid + 768];
        }
        __syncthreads();

        // energy + exp: j = jj*4 + jsub keeps k-reads conflict-free
        #pragma unroll
        for (int jj = 0; jj < 16; ++jj) {
            const int j = jj * 4 + jsub;
            const float4* kp = (const float4*)&kl[j * 8];
            float4 k0 = kp[0], k1 = kp[1];
            float e = qreg[0] * k0.x + qreg[1] * k0.y + qreg[2] * k0.z + qreg[3] * k0.w
                    + qreg[4] * k1.x + qreg[5] * k1.y + qreg[6] * k1.z + qreg[7] * k1.w;
            float p = __expf(e);
            plds[j * 64 + i_e] = p;
            lsum += p;
        }
        __syncthreads();

        // PV: 2 x ds_read_b128 per 16 FMA -> VALU-bound
        #pragma unroll 8
        for (int jj = 0; jj < 64; ++jj) {
            float4 pv = *(const float4*)&plds[jj * 64 + ip];
            float4 vv = *(const float4*)&vl[jj * 64 + c0];
            acc[0]  += pv.x * vv.x; acc[1]  += pv.x * vv.y; acc[2]  += pv.x * vv.z; acc[3]  += pv.x * vv.w;
            acc[4]  += pv.y * vv.x; acc[5]  += pv.y * vv.y; acc[6]  += pv.y * vv.z; acc[7]  += pv.y * vv.w;
            acc[8]  += pv.z * vv.x; acc[9]  += pv.z * vv.y; acc[10] += pv.z * vv.z; acc[11] += pv.z * vv.w;
            acc[12] += pv.w * vv.x; acc[13] += pv.w * vv.y; acc[14] += pv.w * vv.z; acc[15] += pv.w * vv.w;
        }
        __syncthreads();
    }

    // write partial numerator: pout[s][b][c][n], float4 over i
    const int sb = js * BB + b;
    float* pbase = pout + (size_t)sb * 64 * NN;
    #pragma unroll
    for (int cc = 0; cc < 4; ++cc) {
        float4 o4 = make_float4(acc[0 + cc], acc[4 + cc], acc[8 + cc], acc[12 + cc]);
        *(float4*)&pbase[(c0 + cc) * NN + i0 + ip] = o4;
    }

    // reduce lsum over the 4 jsub partials per i (reuse plds, all waves past last sync)
    plds[i_e * 4 + jsub] = lsum;
    __syncthreads();
    if (tid < 64) {
        float l = plds[tid * 4] + plds[tid * 4 + 1] + plds[tid * 4 + 2] + plds[tid * 4 + 3];
        pl[(size_t)sb * NN + i0 + tid] = l;
    }
}

// ---------------------------------------------------------------------------
// Kernel 3: reduce 4 j-splits, normalize, gamma*out + x1 (x1 already in d_out)
// ---------------------------------------------------------------------------
__global__ __launch_bounds__(256) void final_kernel(
    const float* __restrict__ pout, const float* __restrict__ pl,
    const float* __restrict__ gamma,
    float* __restrict__ out)
{
    const int gid = blockIdx.x * 256 + threadIdx.x;   // 0..1048575
    const int b = gid >> 18;
    const int c = (gid >> 12) & 63;
    const int i = gid & 4095;
    const float g = gamma[0];

    float s = 0.f, l = 0.f;
    #pragma unroll
    for (int ss = 0; ss < JSPLIT; ++ss) {
        s += pout[((size_t)(ss * BB + b) * 64 + c) * NN + i];
        l += pl[(size_t)(ss * BB + b) * NN + i];
    }
    float x1 = out[gid];
    out[gid] = g * (s / l) + x1;
}

// ---------------------------------------------------------------------------
extern "C" void kernel_launch(void* const* d_in, const int* in_sizes, int n_in,
                              void* d_out, int out_size, void* d_ws, size_t ws_size,
                              hipStream_t stream) {
    (void)in_sizes; (void)n_in; (void)out_size; (void)ws_size;
    const float* x  = (const float*)d_in[0];
    const float* Wq = (const float*)d_in[1];
    const float* bq = (const float*)d_in[2];
    const float* Wk = (const float*)d_in[3];
    const float* bk = (const float*)d_in[4];
    const float* Wv = (const float*)d_in[5];
    const float* bv = (const float*)d_in[6];
    const float* W1 = (const float*)d_in[7];
    const float* b1 = (const float*)d_in[8];
    const float* gm = (const float*)d_in[9];
    float* out = (float*)d_out;

    float* ws   = (float*)d_ws;
    float* qws  = ws;
    float* kws  = ws + 131072;
    float* vws  = ws + 262144;
    float* pout = ws + 1310720;
    float* pl   = ws + 5505024;

    proj_kernel<<<256, 256, 0, stream>>>(x, Wq, bq, Wk, bk, Wv, bv, W1, b1,
                                         qws, kws, vws, out);
    attn_kernel<<<1024, 256, 0, stream>>>(qws, kws, vws, pout, pl);
    final_kernel<<<4096, 256, 0, stream>>>(pout, pl, gm, out);
}

// Round 3
// 156.583 us; speedup vs baseline: 1.5435x; 1.5435x over previous
//
#include <hip/hip_runtime.h>
#include <hip/hip_bf16.h>

// Problem constants
#define BB 4
#define CC 64
#define NN 4096
#define JSPLIT 2

typedef __attribute__((ext_vector_type(8))) short short8;   // 8 bf16 (4 VGPRs)
typedef __attribute__((ext_vector_type(4))) float f32x4;    // MFMA C/D

// ws layout (float units):
//  qws   bf16 [4][4096][8]                  @f 0        (65536 f)
//  kws   bf16 [4][4096][8]                  @f 65536    (65536 f)
//  vfrag bf16 [4][64][4][2][4][16][8]       @f 131072   (1048576 f)
//        (= [b][jtile][ct][kstep][quad][lane15][jj], B-fragment order)
//  pout  f32  [2][4][64][4096]              @f 1179648  (2097152 f)
//  pl    f32  [2][4][4096]                  @f 3276800  (32768 f)
// total 3,309,568 f = 13.2 MB

__device__ __forceinline__ unsigned short f2bf(float f) {
    unsigned u = __float_as_uint(f);
    return (unsigned short)((u + 0x7FFFu + ((u >> 16) & 1u)) >> 16);
}

// ---------------------------------------------------------------------------
// Kernel 1: fused 1x1 convs. q,k -> bf16 [b][n][8]; v -> bf16 vfrag (B-frag
// order); x1 -> d_out fp32. grid 256 (b * 64 n-tiles), block 256.
// ---------------------------------------------------------------------------
__global__ __launch_bounds__(256) void proj_kernel(
    const float* __restrict__ x,
    const float* __restrict__ Wq, const float* __restrict__ bq,
    const float* __restrict__ Wk, const float* __restrict__ bk,
    const float* __restrict__ Wv, const float* __restrict__ bv,
    const float* __restrict__ W1, const float* __restrict__ b1,
    unsigned short* __restrict__ qb, unsigned short* __restrict__ kb,
    unsigned short* __restrict__ vb,
    float* __restrict__ out)
{
    __shared__ float Wl[144 * 68];
    __shared__ float bl[144];
    __shared__ float xl[64 * 64];

    const int tid = threadIdx.x;

    #pragma unroll
    for (int r = 0; r < 36; ++r) {
        int idx = tid + r * 256;           // 0..9215
        int row = idx >> 6, col = idx & 63;
        float w;
        if (idx < 512)        w = Wq[idx];
        else if (idx < 1024)  w = Wk[idx - 512];
        else if (idx < 5120)  w = Wv[idx - 1024];
        else                  w = W1[idx - 5120];
        Wl[row * 68 + col] = w;
    }
    if (tid < 144) {
        float v;
        if (tid < 8)        v = bq[tid];
        else if (tid < 16)  v = bk[tid - 8];
        else if (tid < 80)  v = bv[tid - 16];
        else                v = b1[tid - 80];
        bl[tid] = v;
    }

    const int blk = blockIdx.x;            // 0..255
    const int b  = blk >> 6;
    const int n0 = (blk & 63) * 64;

    #pragma unroll
    for (int r = 0; r < 16; ++r) {
        int idx = tid + r * 256;           // 0..4095
        int c = idx >> 6, nn = idx & 63;
        xl[c * 64 + nn] = x[(b * 64 + c) * NN + n0 + nn];
    }
    __syncthreads();

    const int n_loc = tid >> 2;
    const int t4    = tid & 3;
    const int n     = n0 + n_loc;

    float xr[64];
    #pragma unroll
    for (int c = 0; c < 64; ++c) xr[c] = xl[c * 64 + n_loc];

    // precompute vfrag coords for this n
    const int vt = n >> 6, vs = (n >> 5) & 1, vq = (n >> 3) & 3, vjj = n & 7;

    for (int oi = 0; oi < 36; ++oi) {
        const int o = t4 * 36 + oi;
        const float4* Wrow = (const float4*)&Wl[o * 68];
        float acc = bl[o];
        #pragma unroll
        for (int c4 = 0; c4 < 16; ++c4) {
            float4 w = Wrow[c4];
            acc += w.x * xr[4 * c4 + 0] + w.y * xr[4 * c4 + 1]
                 + w.z * xr[4 * c4 + 2] + w.w * xr[4 * c4 + 3];
        }
        if (o < 8) {
            qb[(size_t)(b * NN + n) * 8 + o] = f2bf(acc);
        } else if (o < 16) {
            kb[(size_t)(b * NN + n) * 8 + (o - 8)] = f2bf(acc);
        } else if (o < 80) {
            int c = o - 16;
            size_t idx = ((((size_t)((b * 64 + vt) * 4 + (c >> 4)) * 2 + vs) * 4 + vq) * 16
                          + (c & 15)) * 8 + vjj;
            vb[idx] = f2bf(acc);
        } else {
            out[(b * 64 + (o - 80)) * NN + n] = acc;
        }
    }
}

// ---------------------------------------------------------------------------
// Kernel 2: MFMA flash attention. grid 512 = 2 jsplit x 4 b x 64 i-tiles,
// block 256 (4 independent waves, 16 query rows each). No __syncthreads in
// the j-loop: V/K fragments come straight from global (L1/L2-resident),
// P transform goes through wave-private LDS.
// ---------------------------------------------------------------------------
__global__ __launch_bounds__(256) void attn_kernel(
    const unsigned short* __restrict__ qws,
    const unsigned short* __restrict__ kws,
    const unsigned short* __restrict__ vfrag,
    float* __restrict__ pout, float* __restrict__ pl)
{
    __shared__ __align__(16) unsigned short pw[4][16][72];  // per-wave P (bf16), stride 72 keeps 16B align
    __shared__ float olds[4][64][17];                       // per-wave epilogue transpose

    const int tid  = threadIdx.x;
    const int w    = tid >> 6;
    const int lane = tid & 63;
    const int q    = lane >> 4;
    const int l15  = lane & 15;

    const int blk = blockIdx.x;       // 0..511
    const int it  = blk & 63;
    const int b   = (blk >> 6) & 3;
    const int js  = blk >> 8;
    const int i0  = it * 64;

    const short8 z8 = {0, 0, 0, 0, 0, 0, 0, 0};
    const f32x4 zf = {0.f, 0.f, 0.f, 0.f};

    // Q A-fragment: A[m=l15][k=q*8+jj]; only k<8 is real (quad 0)
    short8 qf = z8;
    if (q == 0)
        qf = *(const short8*)&qws[(size_t)(b * NN + i0 + w * 16 + l15) * 8];

    f32x4 acc[4] = {zf, zf, zf, zf};  // PV accumulators, ct = 0..3
    float l4[4] = {0.f, 0.f, 0.f, 0.f};

    for (int t = js * 32; t < js * 32 + 32; ++t) {
        // ---- energy: E[i][j] = Q.K^T via MFMA (K zero-padded 8->32) ----
        f32x4 e[4];
        #pragma unroll
        for (int jt = 0; jt < 4; ++jt) {
            short8 kf = z8;
            if (q == 0)
                kf = *(const short8*)&kws[(size_t)(b * NN + t * 64 + jt * 16 + l15) * 8];
            e[jt] = __builtin_amdgcn_mfma_f32_16x16x32_bf16(qf, kf, zf, 0, 0, 0);
        }
        // ---- exp + row-sum + pack P into wave-private LDS ----
        #pragma unroll
        for (int jt = 0; jt < 4; ++jt) {
            #pragma unroll
            for (int r = 0; r < 4; ++r) {
                float p = __expf(e[jt][r]);       // row = q*4+r, col = jt*16+l15
                l4[r] += p;
                pw[w][q * 4 + r][jt * 16 + l15] = f2bf(p);
            }
        }
        // ---- A-fragments: P[m=l15][k=q*8+jj] (+32 for kstep 1) ----
        short8 a0 = *(const short8*)&pw[w][l15][q * 8];
        short8 a1 = *(const short8*)&pw[w][l15][32 + q * 8];
        // ---- PV: O[i][c] += P.V, V fragments direct from global ----
        const short8* vbase = (const short8*)vfrag + (size_t)(b * 64 + t) * 512 + lane;
        #pragma unroll
        for (int ct = 0; ct < 4; ++ct) {
            short8 v0 = vbase[(ct * 2 + 0) * 64];
            short8 v1 = vbase[(ct * 2 + 1) * 64];
            acc[ct] = __builtin_amdgcn_mfma_f32_16x16x32_bf16(a0, v0, acc[ct], 0, 0, 0);
            acc[ct] = __builtin_amdgcn_mfma_f32_16x16x32_bf16(a1, v1, acc[ct], 0, 0, 0);
        }
    }

    // ---- epilogue (all wave-private, no barriers) ----
    const int sb = js * BB + b;
    #pragma unroll
    for (int r = 0; r < 4; ++r) {
        float v = l4[r];
        v += __shfl_xor(v, 1);  v += __shfl_xor(v, 2);
        v += __shfl_xor(v, 4);  v += __shfl_xor(v, 8);
        l4[r] = v;              // full row-sum for row q*4+r (this j-split)
    }
    if (l15 == 0) {
        #pragma unroll
        for (int r = 0; r < 4; ++r)
            pl[(size_t)sb * NN + i0 + w * 16 + q * 4 + r] = l4[r];
    }
    // transpose D (C-layout) -> [c][i] through LDS, then coalesced stores
    #pragma unroll
    for (int ct = 0; ct < 4; ++ct)
        #pragma unroll
        for (int r = 0; r < 4; ++r)
            olds[w][ct * 16 + l15][q * 4 + r] = acc[ct][r];

    float* pb = pout + ((size_t)sb * 64 + lane) * NN + i0 + w * 16;
    const float* ol = &olds[w][lane][0];
    #pragma unroll
    for (int u = 0; u < 4; ++u) {
        f32x4 o4 = {ol[4 * u + 0], ol[4 * u + 1], ol[4 * u + 2], ol[4 * u + 3]};
        *(f32x4*)&pb[4 * u] = o4;
    }
}

// ---------------------------------------------------------------------------
// Kernel 3: reduce 2 j-splits, normalize, gamma*out + x1 (x1 already in d_out)
// ---------------------------------------------------------------------------
__global__ __launch_bounds__(256) void final_kernel(
    const float* __restrict__ pout, const float* __restrict__ pl,
    const float* __restrict__ gamma,
    float* __restrict__ out)
{
    const int gid = blockIdx.x * 256 + threadIdx.x;   // 0..262143 (float4 units)
    const int b = gid >> 16;
    const int i4 = (gid & 1023) * 4;
    const float g = gamma[0];

    const size_t o0 = (size_t)gid * 4;
    f32x4 s = *(const f32x4*)&pout[o0]
            + *(const f32x4*)&pout[o0 + (size_t)BB * 64 * NN];
    f32x4 l = *(const f32x4*)&pl[(size_t)b * NN + i4]
            + *(const f32x4*)&pl[(size_t)(BB + b) * NN + i4];
    f32x4 x1 = *(const f32x4*)&out[o0];
    f32x4 r = x1;
    #pragma unroll
    for (int u = 0; u < 4; ++u) r[u] += g * (s[u] / l[u]);
    *(f32x4*)&out[o0] = r;
}

// ---------------------------------------------------------------------------
extern "C" void kernel_launch(void* const* d_in, const int* in_sizes, int n_in,
                              void* d_out, int out_size, void* d_ws, size_t ws_size,
                              hipStream_t stream) {
    (void)in_sizes; (void)n_in; (void)out_size; (void)ws_size;
    const float* x  = (const float*)d_in[0];
    const float* Wq = (const float*)d_in[1];
    const float* bq = (const float*)d_in[2];
    const float* Wk = (const float*)d_in[3];
    const float* bk = (const float*)d_in[4];
    const float* Wv = (const float*)d_in[5];
    const float* bv = (const float*)d_in[6];
    const float* W1 = (const float*)d_in[7];
    const float* b1 = (const float*)d_in[8];
    const float* gm = (const float*)d_in[9];
    float* out = (float*)d_out;

    float* ws = (float*)d_ws;
    unsigned short* qb    = (unsigned short*)(ws);             // bf16
    unsigned short* kb    = (unsigned short*)(ws + 65536);     // bf16
    unsigned short* vb    = (unsigned short*)(ws + 131072);    // bf16 (vfrag)
    float*          pout  = ws + 1179648;
    float*          pl    = ws + 3276800;

    proj_kernel<<<256, 256, 0, stream>>>(x, Wq, bq, Wk, bk, Wv, bv, W1, b1,
                                         qb, kb, vb, out);
    attn_kernel<<<512, 256, 0, stream>>>(qb, kb, vb, pout, pl);
    final_kernel<<<1024, 256, 0, stream>>>(pout, pl, gm, out);
}

// Round 4
// 129.188 us; speedup vs baseline: 1.8708x; 1.2121x over previous
//
#include <hip/hip_runtime.h>
#include <hip/hip_bf16.h>

// Problem constants
#define BB 4
#define CC 64
#define NN 4096
#define JSPLIT 4

typedef __attribute__((ext_vector_type(8))) short short8;   // 8 bf16 (4 VGPRs)
typedef __attribute__((ext_vector_type(4))) float f32x4;    // MFMA C/D

// ws layout (float units):
//  qws   bf16 [4][4096][8]                  @f 0        (65536 f)
//  kws   bf16 [4][4096][8]                  @f 65536    (65536 f)
//  vfrag bf16 [4][64][4][2][4][16][8]       @f 131072   (1048576 f)
//        (= [b][jtile][ct][kstep][quad][lane15][jj], B-fragment order)
//  pout  f32  [4][4][64][4096]              @f 1179648  (4194304 f)
//  pl    f32  [4][4][4096]                  @f 5373952  (65536 f)
// total 5,439,488 f = 21.8 MB

__device__ __forceinline__ unsigned short f2bf(float f) {
    unsigned u = __float_as_uint(f);
    return (unsigned short)((u + 0x7FFFu + ((u >> 16) & 1u)) >> 16);
}

// ---------------------------------------------------------------------------
// Kernel 1: fused 1x1 convs. q,k -> bf16 [b][n][8]; v -> bf16 vfrag (B-frag
// order); x1 -> d_out fp32.
// grid 1024 = b * 256 n-tiles of 16 (4 blocks/CU); block 256 = 16 n x 16
// o-groups, 9 outputs/thread (9 independent FMA chains for ILP).
// ---------------------------------------------------------------------------
__global__ __launch_bounds__(256, 4) void proj_kernel(
    const float* __restrict__ x,
    const float* __restrict__ Wq, const float* __restrict__ bq,
    const float* __restrict__ Wk, const float* __restrict__ bk,
    const float* __restrict__ Wv, const float* __restrict__ bv,
    const float* __restrict__ W1, const float* __restrict__ b1,
    unsigned short* __restrict__ qb, unsigned short* __restrict__ kb,
    unsigned short* __restrict__ vb,
    float* __restrict__ out)
{
    __shared__ float Wl[144 * 68];   // rows padded 64->68
    __shared__ float bl[144];
    __shared__ float xl[64 * 16];

    const int tid = threadIdx.x;

    // stage weights: concatenated [Wq(512) | Wk(512) | Wv(4096) | W1(4096)]
    #pragma unroll
    for (int r = 0; r < 36; ++r) {
        int idx = tid + r * 256;           // 0..9215
        int row = idx >> 6, col = idx & 63;
        float w;
        if (idx < 512)        w = Wq[idx];
        else if (idx < 1024)  w = Wk[idx - 512];
        else if (idx < 5120)  w = Wv[idx - 1024];
        else                  w = W1[idx - 5120];
        Wl[row * 68 + col] = w;
    }
    if (tid < 144) {
        float v;
        if (tid < 8)        v = bq[tid];
        else if (tid < 16)  v = bk[tid - 8];
        else if (tid < 80)  v = bv[tid - 16];
        else                v = b1[tid - 80];
        bl[tid] = v;
    }

    const int blk = blockIdx.x;            // 0..1023
    const int b  = blk >> 8;
    const int n0 = (blk & 255) * 16;

    // stage x tile [64c][16n]
    #pragma unroll
    for (int r = 0; r < 4; ++r) {
        int idx = tid + r * 256;           // 0..1023
        int c = idx >> 4, nn = idx & 15;
        xl[c * 16 + nn] = x[(b * 64 + c) * NN + n0 + nn];
    }
    __syncthreads();

    const int n_loc = tid >> 4;
    const int og    = tid & 15;
    const int n     = n0 + n_loc;

    float xr[64];
    #pragma unroll
    for (int c = 0; c < 64; ++c) xr[c] = xl[c * 16 + n_loc];   // broadcast reads

    // precompute vfrag coords for this n
    const int vt = n >> 6, vs = (n >> 5) & 1, vq = (n >> 3) & 3, vjj = n & 7;

    #pragma unroll
    for (int oi = 0; oi < 9; ++oi) {
        const int o = og * 9 + oi;
        const float4* Wrow = (const float4*)&Wl[o * 68];
        float acc = bl[o];
        #pragma unroll
        for (int c4 = 0; c4 < 16; ++c4) {
            float4 w = Wrow[c4];
            acc += w.x * xr[4 * c4 + 0] + w.y * xr[4 * c4 + 1]
                 + w.z * xr[4 * c4 + 2] + w.w * xr[4 * c4 + 3];
        }
        if (o < 8) {
            qb[(size_t)(b * NN + n) * 8 + o] = f2bf(acc);
        } else if (o < 16) {
            kb[(size_t)(b * NN + n) * 8 + (o - 8)] = f2bf(acc);
        } else if (o < 80) {
            int c = o - 16;
            size_t idx = ((((size_t)((b * 64 + vt) * 4 + (c >> 4)) * 2 + vs) * 4 + vq) * 16
                          + (c & 15)) * 8 + vjj;
            vb[idx] = f2bf(acc);
        } else {
            out[(b * 64 + (o - 80)) * NN + n] = acc;
        }
    }
}

// ---------------------------------------------------------------------------
// Kernel 2: MFMA flash attention. grid 1024 = 4 jsplit x 4 b x 64 i-tiles
// (4 blocks/CU, 16 waves/CU); block 256 = 4 independent waves, 16 query rows
// each. No __syncthreads in the j-loop: V/K fragments straight from global
// (L1/L2-resident), P transform through wave-private LDS.
// ---------------------------------------------------------------------------
__global__ __launch_bounds__(256) void attn_kernel(
    const unsigned short* __restrict__ qws,
    const unsigned short* __restrict__ kws,
    const unsigned short* __restrict__ vfrag,
    float* __restrict__ pout, float* __restrict__ pl)
{
    __shared__ __align__(16) unsigned short pw[4][16][72];  // per-wave P (bf16)
    __shared__ float olds[4][64][17];                       // per-wave epilogue transpose

    const int tid  = threadIdx.x;
    const int w    = tid >> 6;
    const int lane = tid & 63;
    const int q    = lane >> 4;
    const int l15  = lane & 15;

    const int blk = blockIdx.x;       // 0..1023
    const int it  = blk & 63;
    const int b   = (blk >> 6) & 3;
    const int js  = blk >> 8;         // 0..3
    const int i0  = it * 64;

    const short8 z8 = {0, 0, 0, 0, 0, 0, 0, 0};
    const f32x4 zf = {0.f, 0.f, 0.f, 0.f};

    // Q A-fragment: A[m=l15][k=q*8+jj]; only k<8 is real (quad 0)
    short8 qf = z8;
    if (q == 0)
        qf = *(const short8*)&qws[(size_t)(b * NN + i0 + w * 16 + l15) * 8];

    f32x4 acc[4] = {zf, zf, zf, zf};  // PV accumulators, ct = 0..3
    float l4[4] = {0.f, 0.f, 0.f, 0.f};

    for (int t = js * 16; t < js * 16 + 16; ++t) {
        // ---- energy: E[i][j] = Q.K^T via MFMA (K zero-padded 8->32) ----
        f32x4 e[4];
        #pragma unroll
        for (int jt = 0; jt < 4; ++jt) {
            short8 kf = z8;
            if (q == 0)
                kf = *(const short8*)&kws[(size_t)(b * NN + t * 64 + jt * 16 + l15) * 8];
            e[jt] = __builtin_amdgcn_mfma_f32_16x16x32_bf16(qf, kf, zf, 0, 0, 0);
        }
        // ---- exp + row-sum + pack P into wave-private LDS ----
        #pragma unroll
        for (int jt = 0; jt < 4; ++jt) {
            #pragma unroll
            for (int r = 0; r < 4; ++r) {
                float p = __expf(e[jt][r]);       // row = q*4+r, col = jt*16+l15
                l4[r] += p;
                pw[w][q * 4 + r][jt * 16 + l15] = f2bf(p);
            }
        }
        // ---- A-fragments: P[m=l15][k=q*8+jj] (+32 for kstep 1) ----
        short8 a0 = *(const short8*)&pw[w][l15][q * 8];
        short8 a1 = *(const short8*)&pw[w][l15][32 + q * 8];
        // ---- PV: O[i][c] += P.V, V fragments direct from global ----
        const short8* vbase = (const short8*)vfrag + (size_t)(b * 64 + t) * 512 + lane;
        #pragma unroll
        for (int ct = 0; ct < 4; ++ct) {
            short8 v0 = vbase[(ct * 2 + 0) * 64];
            short8 v1 = vbase[(ct * 2 + 1) * 64];
            acc[ct] = __builtin_amdgcn_mfma_f32_16x16x32_bf16(a0, v0, acc[ct], 0, 0, 0);
            acc[ct] = __builtin_amdgcn_mfma_f32_16x16x32_bf16(a1, v1, acc[ct], 0, 0, 0);
        }
    }

    // ---- epilogue (all wave-private, no barriers) ----
    const int sb = js * BB + b;
    #pragma unroll
    for (int r = 0; r < 4; ++r) {
        float v = l4[r];
        v += __shfl_xor(v, 1);  v += __shfl_xor(v, 2);
        v += __shfl_xor(v, 4);  v += __shfl_xor(v, 8);
        l4[r] = v;              // full row-sum for row q*4+r (this j-split)
    }
    if (l15 == 0) {
        #pragma unroll
        for (int r = 0; r < 4; ++r)
            pl[(size_t)sb * NN + i0 + w * 16 + q * 4 + r] = l4[r];
    }
    // transpose D (C-layout) -> [c][i] through LDS, then coalesced stores
    #pragma unroll
    for (int ct = 0; ct < 4; ++ct)
        #pragma unroll
        for (int r = 0; r < 4; ++r)
            olds[w][ct * 16 + l15][q * 4 + r] = acc[ct][r];

    float* pb = pout + ((size_t)sb * 64 + lane) * NN + i0 + w * 16;
    const float* ol = &olds[w][lane][0];
    #pragma unroll
    for (int u = 0; u < 4; ++u) {
        f32x4 o4 = {ol[4 * u + 0], ol[4 * u + 1], ol[4 * u + 2], ol[4 * u + 3]};
        *(f32x4*)&pb[4 * u] = o4;
    }
}

// ---------------------------------------------------------------------------
// Kernel 3: reduce 4 j-splits, normalize, gamma*out + x1 (x1 already in d_out)
// ---------------------------------------------------------------------------
__global__ __launch_bounds__(256) void final_kernel(
    const float* __restrict__ pout, const float* __restrict__ pl,
    const float* __restrict__ gamma,
    float* __restrict__ out)
{
    const int gid = blockIdx.x * 256 + threadIdx.x;   // 0..262143 (float4 units)
    const int b = gid >> 16;
    const int i4 = (gid & 1023) * 4;
    const float g = gamma[0];

    const size_t o0 = (size_t)gid * 4;
    f32x4 s = {0.f, 0.f, 0.f, 0.f};
    f32x4 l = {0.f, 0.f, 0.f, 0.f};
    #pragma unroll
    for (int ss = 0; ss < JSPLIT; ++ss) {
        s += *(const f32x4*)&pout[o0 + (size_t)ss * BB * 64 * NN];
        l += *(const f32x4*)&pl[(size_t)(ss * BB + b) * NN + i4];
    }
    f32x4 x1 = *(const f32x4*)&out[o0];
    f32x4 r = x1;
    #pragma unroll
    for (int u = 0; u < 4; ++u) r[u] += g * (s[u] / l[u]);
    *(f32x4*)&out[o0] = r;
}

// ---------------------------------------------------------------------------
extern "C" void kernel_launch(void* const* d_in, const int* in_sizes, int n_in,
                              void* d_out, int out_size, void* d_ws, size_t ws_size,
                              hipStream_t stream) {
    (void)in_sizes; (void)n_in; (void)out_size; (void)ws_size;
    const float* x  = (const float*)d_in[0];
    const float* Wq = (const float*)d_in[1];
    const float* bq = (const float*)d_in[2];
    const float* Wk = (const float*)d_in[3];
    const float* bk = (const float*)d_in[4];
    const float* Wv = (const float*)d_in[5];
    const float* bv = (const float*)d_in[6];
    const float* W1 = (const float*)d_in[7];
    const float* b1 = (const float*)d_in[8];
    const float* gm = (const float*)d_in[9];
    float* out = (float*)d_out;

    float* ws = (float*)d_ws;
    unsigned short* qb    = (unsigned short*)(ws);             // bf16
    unsigned short* kb    = (unsigned short*)(ws + 65536);     // bf16
    unsigned short* vb    = (unsigned short*)(ws + 131072);    // bf16 (vfrag)
    float*          pout  = ws + 1179648;
    float*          pl    = ws + 5373952;

    proj_kernel<<<1024, 256, 0, stream>>>(x, Wq, bq, Wk, bk, Wv, bv, W1, b1,
                                          qb, kb, vb, out);
    attn_kernel<<<1024, 256, 0, stream>>>(qb, kb, vb, pout, pl);
    final_kernel<<<1024, 256, 0, stream>>>(pout, pl, gm, out);
}

// Round 5
// 117.281 us; speedup vs baseline: 2.0608x; 1.1015x over previous
//
#include <hip/hip_runtime.h>
#include <hip/hip_bf16.h>

// Problem constants
#define BB 4
#define CC 64
#define NN 4096
#define JSPLIT 4

typedef __attribute__((ext_vector_type(8))) short short8;   // 8 bf16 (4 VGPRs)
typedef __attribute__((ext_vector_type(4))) float f32x4;    // MFMA C/D

// ws layout (float units):
//  qb    bf16 [4][4096][8]                  @f 0        (65536 f)
//  kb    bf16 [4][4096][8]                  @f 65536    (65536 f)
//  vb    bf16 [4][64][4][2][4][16][8]       @f 131072   (1048576 f)
//        (= [b][jtile][ct][kstep][quad][lane15][jj], B-fragment order)
//  pout  f32  [4][4][64][4096]              @f 1179648  (4194304 f)
//  pl    f32  [4][4][4096]                  @f 5373952  (65536 f)

__device__ __forceinline__ unsigned short f2bf(float f) {
    unsigned u = __float_as_uint(f);
    return (unsigned short)((u + 0x7FFFu + ((u >> 16) & 1u)) >> 16);
}

// async global->LDS, 16B per lane; lds dest = wave-uniform base + lane*16
#define GLD_LDS16(g, l)                                                        \
    __builtin_amdgcn_global_load_lds(                                          \
        (const __attribute__((address_space(1))) unsigned int*)(g),            \
        (__attribute__((address_space(3))) unsigned int*)(l), 16, 0, 0)

// ---------------------------------------------------------------------------
// Kernel 1: fused 1x1 convs via MFMA. W (144x64) staged as bf16 A-fragments,
// x-tile (64c x 16n) staged transposed as bf16 B-fragments. 18 MFMA per block.
// q,k -> bf16 [b][n][8]; v -> bf16 vfrag; x1 -> d_out fp32 (+bias everywhere).
// grid 1024 = 4 b x 256 n-tiles of 16; block 256 (4 waves share chunks).
// ---------------------------------------------------------------------------
__global__ __launch_bounds__(256) void proj_kernel(
    const float* __restrict__ x,
    const float* __restrict__ Wq, const float* __restrict__ bq,
    const float* __restrict__ Wk, const float* __restrict__ bk,
    const float* __restrict__ Wv, const float* __restrict__ bv,
    const float* __restrict__ W1, const float* __restrict__ b1,
    unsigned short* __restrict__ qb, unsigned short* __restrict__ kb,
    unsigned short* __restrict__ vb,
    float* __restrict__ out)
{
    __shared__ __align__(16) unsigned short wfrag[18 * 64 * 8]; // 18 KB: [chunk*2+kstep][lane][8]
    __shared__ __align__(16) unsigned short xh[16 * 80];        // 2.5 KB: [n][c] bf16, stride 80
    __shared__ float bl[144];

    const int tid = threadIdx.x;
    const int blk = blockIdx.x;        // 0..1023
    const int b  = blk >> 8;
    const int n0 = (blk & 255) * 16;

    // stage W fragments (bf16): entry e = (chunk*2+kstep)*64 + lane
    for (int e = tid; e < 1152; e += 256) {
        int cf = e >> 6;               // chunk*2+kstep
        int lane = e & 63;
        int o  = (cf >> 1) * 16 + (lane & 15);
        int c0 = (cf & 1) * 32 + (lane >> 4) * 8;
        const float* row = (o < 8)  ? (Wq + o * 64)
                         : (o < 16) ? (Wk + (o - 8) * 64)
                         : (o < 80) ? (Wv + (o - 16) * 64)
                                    : (W1 + (o - 80) * 64);
        float4 aa = *(const float4*)(row + c0);
        float4 bb = *(const float4*)(row + c0 + 4);
        short8 s;
        s[0] = f2bf(aa.x); s[1] = f2bf(aa.y); s[2] = f2bf(aa.z); s[3] = f2bf(aa.w);
        s[4] = f2bf(bb.x); s[5] = f2bf(bb.y); s[6] = f2bf(bb.z); s[7] = f2bf(bb.w);
        *(short8*)&wfrag[e * 8] = s;
    }
    if (tid < 144) {
        bl[tid] = (tid < 8) ? bq[tid] : (tid < 16) ? bk[tid - 8]
                : (tid < 80) ? bv[tid - 16] : b1[tid - 80];
    }
    // stage x tile transposed -> bf16 [n][c]
    for (int e = tid; e < 1024; e += 256) {
        int c = e >> 4, nl = e & 15;
        xh[nl * 80 + c] = f2bf(x[(b * 64 + c) * NN + n0 + nl]);
    }
    __syncthreads();

    const int w = tid >> 6, lane = tid & 63;
    const int q = lane >> 4, l15 = lane & 15;
    const int n = n0 + l15;

    const short8 xf0 = *(const short8*)&xh[l15 * 80 + q * 8];
    const short8 xf1 = *(const short8*)&xh[l15 * 80 + 32 + q * 8];
    const f32x4 zf = {0.f, 0.f, 0.f, 0.f};

    // precompute vfrag coords for this n
    const int vt = n >> 6, vs = (n >> 5) & 1, vq = (n >> 3) & 3, vjj = n & 7;

    // wave w handles chunks {w, w+4}; wave 0 also chunk 8
    #pragma unroll
    for (int ci = 0; ci < 3; ++ci) {
        if (ci == 2 && w != 0) break;
        const int chunk = (ci == 2) ? 8 : (w + ci * 4);
        f32x4 d = __builtin_amdgcn_mfma_f32_16x16x32_bf16(
            *(const short8*)&wfrag[((chunk * 2 + 0) * 64 + lane) * 8], xf0, zf, 0, 0, 0);
        d = __builtin_amdgcn_mfma_f32_16x16x32_bf16(
            *(const short8*)&wfrag[((chunk * 2 + 1) * 64 + lane) * 8], xf1, d, 0, 0, 0);
        // D: row o = chunk*16 + q*4 + r, col n = l15
        #pragma unroll
        for (int r = 0; r < 4; ++r) {
            const int o = chunk * 16 + q * 4 + r;
            const float val = d[r] + bl[o];
            if (o < 8) {
                qb[(size_t)(b * NN + n) * 8 + o] = f2bf(val);
            } else if (o < 16) {
                kb[(size_t)(b * NN + n) * 8 + (o - 8)] = f2bf(val);
            } else if (o < 80) {
                const int c = o - 16;
                size_t idx = ((((size_t)((b * 64 + vt) * 4 + (c >> 4)) * 2 + vs) * 4 + vq) * 16
                              + (c & 15)) * 8 + vjj;
                vb[idx] = f2bf(val);
            } else {
                out[(size_t)(b * 64 + (o - 80)) * NN + n] = val;
            }
        }
    }
}

// ---------------------------------------------------------------------------
// Kernel 2: MFMA flash attention with LDS-staged V/K (global_load_lds,
// double-buffered, prefetch-before-compute). grid 1024 = 4 jsplit x 4 b x
// 64 i-tiles (4 blocks/CU); block 256 = 4 waves, 16 query rows each.
// ---------------------------------------------------------------------------
__global__ __launch_bounds__(256) void attn_kernel(
    const unsigned short* __restrict__ qws,
    const unsigned short* __restrict__ kws,
    const unsigned short* __restrict__ vfrag,
    float* __restrict__ pout, float* __restrict__ pl)
{
    union SmemU {
        unsigned char stage[2][9216];   // per buf: V tile 8192 B + K tile 1024 B
        float olds[4][64][17];          // epilogue transpose (17408 B)
    };
    __shared__ __align__(16) SmemU su;
    __shared__ __align__(16) unsigned short pw[4][16][80];  // per-wave P (bf16), stride 80

    const int tid  = threadIdx.x;
    const int w    = tid >> 6;
    const int lane = tid & 63;
    const int q    = lane >> 4;
    const int l15  = lane & 15;

    const int blk = blockIdx.x;       // 0..1023
    const int it  = blk & 63;
    const int b   = (blk >> 6) & 3;
    const int js  = blk >> 8;         // 0..3
    const int i0  = it * 64;

    const short8 z8 = {0, 0, 0, 0, 0, 0, 0, 0};
    const f32x4 zf = {0.f, 0.f, 0.f, 0.f};

    // Q A-fragment: A[m=l15][k=q*8+jj]; only k<8 real (quad 0), K zero-padded
    short8 qf = z8;
    if (q == 0)
        qf = *(const short8*)&qws[(size_t)(b * NN + i0 + w * 16 + l15) * 8];

    f32x4 acc[4] = {zf, zf, zf, zf};
    float l4[4] = {0.f, 0.f, 0.f, 0.f};

    const int t0 = js * 16;

    // wave w stages V chunks {w, w+4} (1 KB each); wave 0 also stages K (1 KB)
#define STAGE(p, t) do {                                                          \
        const unsigned char* vt_ = (const unsigned char*)(vfrag                   \
                                    + (size_t)(b * 64 + (t)) * 4096);             \
        GLD_LDS16(vt_ + (size_t)w * 1024 + lane * 16, &su.stage[p][w * 1024]);    \
        GLD_LDS16(vt_ + (size_t)(w + 4) * 1024 + lane * 16,                       \
                  &su.stage[p][(w + 4) * 1024]);                                  \
        if (w == 0) {                                                             \
            const unsigned char* kt_ = (const unsigned char*)(kws                 \
                                        + (size_t)(b * NN + (t) * 64) * 8);       \
            GLD_LDS16(kt_ + lane * 16, &su.stage[p][8192]);                       \
        }                                                                         \
    } while (0)

    STAGE(0, t0);
    for (int idx = 0; idx < 16; ++idx) {
        __syncthreads();   // stage(idx) complete; compute(idx-1) done
        if (idx + 1 < 16) STAGE((idx + 1) & 1, t0 + idx + 1);  // in flight during compute

        const unsigned short* vl = (const unsigned short*)&su.stage[idx & 1][0];
        const unsigned short* kl = (const unsigned short*)&su.stage[idx & 1][8192];

        // ---- energy: E[i][j] = Q.K^T (K zero-padded 8->32) ----
        f32x4 e[4];
        #pragma unroll
        for (int jt = 0; jt < 4; ++jt) {
            short8 kf = z8;
            if (q == 0)
                kf = *(const short8*)&kl[(jt * 16 + l15) * 8];
            e[jt] = __builtin_amdgcn_mfma_f32_16x16x32_bf16(qf, kf, zf, 0, 0, 0);
        }
        // ---- exp + row-sum + pack P (wave-private LDS) ----
        #pragma unroll
        for (int jt = 0; jt < 4; ++jt) {
            #pragma unroll
            for (int r = 0; r < 4; ++r) {
                float p = __expf(e[jt][r]);       // row q*4+r, col jt*16+l15
                l4[r] += p;
                pw[w][q * 4 + r][jt * 16 + l15] = f2bf(p);
            }
        }
        // ---- A-fragments of P ----
        short8 a0 = *(const short8*)&pw[w][l15][q * 8];
        short8 a1 = *(const short8*)&pw[w][l15][32 + q * 8];
        // ---- PV: O += P.V from staged LDS ----
        const short8* vb8 = (const short8*)vl;
        #pragma unroll
        for (int ct = 0; ct < 4; ++ct) {
            short8 v0 = vb8[(ct * 2 + 0) * 64 + lane];
            short8 v1 = vb8[(ct * 2 + 1) * 64 + lane];
            acc[ct] = __builtin_amdgcn_mfma_f32_16x16x32_bf16(a0, v0, acc[ct], 0, 0, 0);
            acc[ct] = __builtin_amdgcn_mfma_f32_16x16x32_bf16(a1, v1, acc[ct], 0, 0, 0);
        }
    }
#undef STAGE

    // ---- epilogue ----
    __syncthreads();   // all staging reads done before olds overwrites the union
    const int sb = js * BB + b;
    #pragma unroll
    for (int r = 0; r < 4; ++r) {
        float v = l4[r];
        v += __shfl_xor(v, 1);  v += __shfl_xor(v, 2);
        v += __shfl_xor(v, 4);  v += __shfl_xor(v, 8);
        l4[r] = v;
    }
    if (l15 == 0) {
        #pragma unroll
        for (int r = 0; r < 4; ++r)
            pl[(size_t)sb * NN + i0 + w * 16 + q * 4 + r] = l4[r];
    }
    #pragma unroll
    for (int ct = 0; ct < 4; ++ct)
        #pragma unroll
        for (int r = 0; r < 4; ++r)
            su.olds[w][ct * 16 + l15][q * 4 + r] = acc[ct][r];

    float* pb = pout + ((size_t)sb * 64 + lane) * NN + i0 + w * 16;
    const float* ol = &su.olds[w][lane][0];
    #pragma unroll
    for (int u = 0; u < 4; ++u) {
        f32x4 o4 = {ol[4 * u + 0], ol[4 * u + 1], ol[4 * u + 2], ol[4 * u + 3]};
        *(f32x4*)&pb[4 * u] = o4;
    }
}

// ---------------------------------------------------------------------------
// Kernel 3: reduce 4 j-splits, normalize, gamma*out + x1 (x1 already in d_out)
// ---------------------------------------------------------------------------
__global__ __launch_bounds__(256) void final_kernel(
    const float* __restrict__ pout, const float* __restrict__ pl,
    const float* __restrict__ gamma,
    float* __restrict__ out)
{
    const int gid = blockIdx.x * 256 + threadIdx.x;   // float4 units
    const int b = gid >> 16;
    const int i4 = (gid & 1023) * 4;
    const float g = gamma[0];

    const size_t o0 = (size_t)gid * 4;
    f32x4 s = {0.f, 0.f, 0.f, 0.f};
    f32x4 l = {0.f, 0.f, 0.f, 0.f};
    #pragma unroll
    for (int ss = 0; ss < JSPLIT; ++ss) {
        s += *(const f32x4*)&pout[o0 + (size_t)ss * BB * 64 * NN];
        l += *(const f32x4*)&pl[(size_t)(ss * BB + b) * NN + i4];
    }
    f32x4 x1 = *(const f32x4*)&out[o0];
    f32x4 r = x1;
    #pragma unroll
    for (int u = 0; u < 4; ++u) r[u] += g * (s[u] / l[u]);
    *(f32x4*)&out[o0] = r;
}

// ---------------------------------------------------------------------------
extern "C" void kernel_launch(void* const* d_in, const int* in_sizes, int n_in,
                              void* d_out, int out_size, void* d_ws, size_t ws_size,
                              hipStream_t stream) {
    (void)in_sizes; (void)n_in; (void)out_size; (void)ws_size;
    const float* x  = (const float*)d_in[0];
    const float* Wq = (const float*)d_in[1];
    const float* bq = (const float*)d_in[2];
    const float* Wk = (const float*)d_in[3];
    const float* bk = (const float*)d_in[4];
    const float* Wv = (const float*)d_in[5];
    const float* bv = (const float*)d_in[6];
    const float* W1 = (const float*)d_in[7];
    const float* b1 = (const float*)d_in[8];
    const float* gm = (const float*)d_in[9];
    float* out = (float*)d_out;

    float* ws = (float*)d_ws;
    unsigned short* qb   = (unsigned short*)(ws);             // bf16
    unsigned short* kb   = (unsigned short*)(ws + 65536);     // bf16
    unsigned short* vb   = (unsigned short*)(ws + 131072);    // bf16 (vfrag)
    float*          pout = ws + 1179648;
    float*          pl   = ws + 5373952;

    proj_kernel<<<1024, 256, 0, stream>>>(x, Wq, bq, Wk, bk, Wv, bv, W1, b1,
                                          qb, kb, vb, out);
    attn_kernel<<<1024, 256, 0, stream>>>(qb, kb, vb, pout, pl);
    final_kernel<<<1024, 256, 0, stream>>>(pout, pl, gm, out);
}